// Round 6
// baseline (401.549 us; speedup 1.0000x reference)
//
#include <hip/hip_runtime.h>
#include <hip/hip_fp16.h>
#include <stdint.h>

#define BB 512
#define TT 1024
#define II 15
#define HH 64
#define OO 11

typedef __fp16 half2v __attribute__((ext_vector_type(2)));
typedef int int2v __attribute__((ext_vector_type(2)));
typedef int int4v __attribute__((ext_vector_type(4)));

union PK { int i; half2v h; float f; };

__device__ __forceinline__ half2v i2h2(int v) { PK u; u.i = v; return u.h; }
__device__ __forceinline__ int h22i(half2v v) { PK u; u.h = v; return u.i; }

__device__ __forceinline__ float FDOT2(half2v a, half2v b, float c) {
    return __builtin_amdgcn_fdot2(a, b, c, false);
}

// Fused RNN: one wave per batch, lane = h_out index. Per step:
//   GEMV: h broadcast via LDS (ds_write_b16 of own h; 8 uniform-address
//         ds_read_b128 return all 64 h as natural f16 pairs), 32 dot2 over
//         8 accumulators (depth 4) + 3-level tree.
//   Decoder (fused, OFF the critical path): lane g*16+c computes a K=16
//   slice of out[b][t][c] from 2 ds_read_b64 of the same hbuf, 8 dot2,
//   then shfl_xor(16,32) reduce over the 4 g-lanes; g==0,c<11 stores f32.
// No hs workspace at all: out written directly, h_last f32 at end.
__global__ __launch_bounds__(64) void rnn_fused(
    const float* __restrict__ x, const float* __restrict__ W_ih,
    const float* __restrict__ b_ih, const float* __restrict__ W_hh,
    const float* __restrict__ b_hh, const float* __restrict__ W_dec,
    const float* __restrict__ b_dec, float* __restrict__ out,
    float* __restrict__ h_last)
{
    __shared__ __align__(16) int xbuf[64 * 8];     // [step][8 packed x pairs]
    __shared__ __align__(16) _Float16 hbuf[64];    // h_t, one f16 per lane
    const int b = blockIdx.x;
    const int lane = threadIdx.x;
    const int c = lane & 15;        // decoder output column
    const int g = lane >> 4;        // decoder K-slice [16g, 16g+16)

    // recurrent weights: whh[j] = (W_hh[lane][2j], W_hh[lane][2j+1])
    half2v whh[32];
#pragma unroll
    for (int j = 0; j < 32; ++j)
        whh[j] = __builtin_amdgcn_cvt_pkrtz(W_hh[lane * HH + 2 * j],
                                            W_hh[lane * HH + 2 * j + 1]);
    // input weights; pair 7 = (w14, bias) matching x pair (x14, 1.0)
    half2v wx[8];
#pragma unroll
    for (int j = 0; j < 7; ++j)
        wx[j] = __builtin_amdgcn_cvt_pkrtz(W_ih[lane * II + 2 * j],
                                           W_ih[lane * II + 2 * j + 1]);
    wx[7] = __builtin_amdgcn_cvt_pkrtz(W_ih[lane * II + 14],
                                       b_ih[lane] + b_hh[lane]);
    // decoder weights: lane (g,c) holds W_dec[c][16g..16g+15] as 8 pairs
    const int cw = (c < OO) ? c : OO - 1;
    half2v wd[8];
#pragma unroll
    for (int j = 0; j < 8; ++j)
        wd[j] = __builtin_amdgcn_cvt_pkrtz(W_dec[cw * HH + g * 16 + 2 * j],
                                           W_dec[cw * HH + g * 16 + 2 * j + 1]);
    const float bd = b_dec[cw];
    const bool emit = (g == 0) && (c < OO);

    const float* xb = x + (size_t)b * TT * II;
    float* outb = out + (size_t)b * TT * OO;

    // stage x chunk 0: lane ts packs x[b][ts][0..14] -> 8 pairs in xbuf
    {
        float cf[II];
#pragma unroll
        for (int i = 0; i < II; ++i) cf[i] = xb[lane * II + i];
        int4v p0, p1;
        p0.x = h22i(__builtin_amdgcn_cvt_pkrtz(cf[0], cf[1]));
        p0.y = h22i(__builtin_amdgcn_cvt_pkrtz(cf[2], cf[3]));
        p0.z = h22i(__builtin_amdgcn_cvt_pkrtz(cf[4], cf[5]));
        p0.w = h22i(__builtin_amdgcn_cvt_pkrtz(cf[6], cf[7]));
        p1.x = h22i(__builtin_amdgcn_cvt_pkrtz(cf[8], cf[9]));
        p1.y = h22i(__builtin_amdgcn_cvt_pkrtz(cf[10], cf[11]));
        p1.z = h22i(__builtin_amdgcn_cvt_pkrtz(cf[12], cf[13]));
        p1.w = h22i(__builtin_amdgcn_cvt_pkrtz(cf[14], 1.0f));
        *(int4v*)&xbuf[lane * 8] = p0;
        *(int4v*)&xbuf[lane * 8 + 4] = p1;
    }
    hbuf[lane] = (_Float16)0.0f;    // h(-1) = 0

    float h = 0.0f;

    for (int tc = 0; tc < TT; tc += 64) {
        // prefetch next x chunk into registers (consumed at chunk end)
        const int tnb = (tc + 64 < TT) ? (tc + 64) : tc;
        float nf[II];
#pragma unroll
        for (int i = 0; i < II; ++i)
            nf[i] = xb[(size_t)(tnb + lane) * II + i];

#pragma unroll 4
        for (int ts = 0; ts < 64; ++ts) {
            // broadcast reads: x pairs + all 32 h pairs (uniform addresses)
            const int4v xv0 = *(const int4v*)&xbuf[ts * 8];
            const int4v xv1 = *(const int4v*)&xbuf[ts * 8 + 4];
            int4v hb[8];
#pragma unroll
            for (int q = 0; q < 8; ++q)
                hb[q] = *(const int4v*)&hbuf[q * 8];

            // 8 accumulators: init from xproj, GEMV depth 4 each
            float a0 = FDOT2(i2h2(xv0.x), wx[0], 0.0f);
            float a1 = FDOT2(i2h2(xv0.y), wx[1], 0.0f);
            float a2 = FDOT2(i2h2(xv0.z), wx[2], 0.0f);
            float a3 = FDOT2(i2h2(xv0.w), wx[3], 0.0f);
            float a4 = FDOT2(i2h2(xv1.x), wx[4], 0.0f);
            float a5 = FDOT2(i2h2(xv1.y), wx[5], 0.0f);
            float a6 = FDOT2(i2h2(xv1.z), wx[6], 0.0f);
            float a7 = FDOT2(i2h2(xv1.w), wx[7], 0.0f);
#pragma unroll
            for (int q = 0; q < 4; ++q) {
                a0 = FDOT2(i2h2(hb[2 * q].x), whh[8 * q + 0], a0);
                a1 = FDOT2(i2h2(hb[2 * q].y), whh[8 * q + 1], a1);
                a2 = FDOT2(i2h2(hb[2 * q].z), whh[8 * q + 2], a2);
                a3 = FDOT2(i2h2(hb[2 * q].w), whh[8 * q + 3], a3);
                a4 = FDOT2(i2h2(hb[2 * q + 1].x), whh[8 * q + 4], a4);
                a5 = FDOT2(i2h2(hb[2 * q + 1].y), whh[8 * q + 5], a5);
                a6 = FDOT2(i2h2(hb[2 * q + 1].z), whh[8 * q + 6], a6);
                a7 = FDOT2(i2h2(hb[2 * q + 1].w), whh[8 * q + 7], a7);
            }
            h = fmaxf(((a0 + a1) + (a2 + a3)) + ((a4 + a5) + (a6 + a7)), 0.0f);

            // publish h_t (f16 scalar; pairs form naturally in LDS)
            hbuf[lane] = (_Float16)h;

            // fused decoder (off the h->h critical path): read own K-slice
            const int2v hd0 = *(const int2v*)&hbuf[g * 16];
            const int2v hd1 = *(const int2v*)&hbuf[g * 16 + 4];
            float d0 = FDOT2(i2h2(hd0.x), wd[0], 0.0f);
            float d1 = FDOT2(i2h2(hd0.y), wd[1], 0.0f);
            d0 = FDOT2(i2h2(hd1.x), wd[2], d0);
            d1 = FDOT2(i2h2(hd1.y), wd[3], d1);
            const int2v hd2 = *(const int2v*)&hbuf[g * 16 + 8];
            const int2v hd3 = *(const int2v*)&hbuf[g * 16 + 12];
            d0 = FDOT2(i2h2(hd2.x), wd[4], d0);
            d1 = FDOT2(i2h2(hd2.y), wd[5], d1);
            d0 = FDOT2(i2h2(hd3.x), wd[6], d0);
            d1 = FDOT2(i2h2(hd3.y), wd[7], d1);
            float d = d0 + d1;
            d += __shfl_xor(d, 16);
            d += __shfl_xor(d, 32);
            if (emit)
                outb[(size_t)(tc + ts) * OO + c] = fmaxf(d + bd, 0.0f);
        }

        // commit prefetched x chunk (in-order DS: later reads see it)
        int4v p0, p1;
        p0.x = h22i(__builtin_amdgcn_cvt_pkrtz(nf[0], nf[1]));
        p0.y = h22i(__builtin_amdgcn_cvt_pkrtz(nf[2], nf[3]));
        p0.z = h22i(__builtin_amdgcn_cvt_pkrtz(nf[4], nf[5]));
        p0.w = h22i(__builtin_amdgcn_cvt_pkrtz(nf[6], nf[7]));
        p1.x = h22i(__builtin_amdgcn_cvt_pkrtz(nf[8], nf[9]));
        p1.y = h22i(__builtin_amdgcn_cvt_pkrtz(nf[10], nf[11]));
        p1.z = h22i(__builtin_amdgcn_cvt_pkrtz(nf[12], nf[13]));
        p1.w = h22i(__builtin_amdgcn_cvt_pkrtz(nf[14], 1.0f));
        *(int4v*)&xbuf[lane * 8] = p0;
        *(int4v*)&xbuf[lane * 8 + 4] = p1;
    }
    h_last[b * HH + lane] = h;
}

extern "C" void kernel_launch(void* const* d_in, const int* in_sizes, int n_in,
                              void* d_out, int out_size, void* d_ws, size_t ws_size,
                              hipStream_t stream) {
    const float* x     = (const float*)d_in[0];
    const float* W_ih  = (const float*)d_in[1];
    const float* b_ih  = (const float*)d_in[2];
    const float* W_hh  = (const float*)d_in[3];
    const float* b_hh  = (const float*)d_in[4];
    const float* W_dec = (const float*)d_in[5];
    const float* b_dec = (const float*)d_in[6];

    float* out    = (float*)d_out;
    float* h_last = out + (size_t)BB * TT * OO;   // second tuple output

    rnn_fused<<<BB, 64, 0, stream>>>(x, W_ih, b_ih, W_hh, b_hh,
                                     W_dec, b_dec, out, h_last);
}

// Round 7
// 273.809 us; speedup vs baseline: 1.4665x; 1.4665x over previous
//
#include <hip/hip_runtime.h>
#include <hip/hip_fp16.h>
#include <stdint.h>

#define BB 512
#define TT 1024
#define II 15
#define HH 64
#define OO 11

typedef __fp16 half2v __attribute__((ext_vector_type(2)));
typedef _Float16 half8 __attribute__((ext_vector_type(8)));
typedef float floatx4 __attribute__((ext_vector_type(4)));
typedef int int4v __attribute__((ext_vector_type(4)));

union PK { int i; half2v h; float f; };

__device__ __forceinline__ half2v i2h2(int v) { PK u; u.i = v; return u.h; }
__device__ __forceinline__ int h22i(half2v v) { PK u; u.h = v; return u.i; }

__device__ __forceinline__ float FDOT2(half2v a, half2v b, float c) {
    return __builtin_amdgcn_fdot2(a, b, c, false);
}

// One wave per batch, lane = h_out. Critical path per step is exactly:
// ds_write_b16(h) -> 8x uniform-address ds_read_b128 (broadcast) -> depth-4
// dot2 chains -> tree -> relu. Everything else is hoisted off it:
//  - input projection for step t+1 computed during step t (xa[8] accumulators),
//    with its xbuf reads issued BEFORE the h(t) write (in-order DS pipe).
//  - x staged per 64-step chunk into a DOUBLE-buffered xbuf so the one-step-
//    ahead read is valid across chunk boundaries.
__global__ __launch_bounds__(64) void rnn_rec(
    const float* __restrict__ x, const float* __restrict__ W_ih,
    const float* __restrict__ b_ih, const float* __restrict__ W_hh,
    const float* __restrict__ b_hh, _Float16* __restrict__ hs,
    float* __restrict__ h_last)
{
    __shared__ __align__(16) int xbuf[2][64 * 8];  // [buf][step][8 packed pairs]
    __shared__ __align__(16) _Float16 hbuf[64];    // h_t, one f16 per lane
    const int b = blockIdx.x;
    const int lane = threadIdx.x;

    // recurrent weights: whh[p] = (W_hh[lane][2p], W_hh[lane][2p+1])
    half2v whh[32];
#pragma unroll
    for (int p = 0; p < 32; ++p)
        whh[p] = __builtin_amdgcn_cvt_pkrtz(W_hh[lane * HH + 2 * p],
                                            W_hh[lane * HH + 2 * p + 1]);
    // input weights; pair 7 = (w14, bias) matching x pair (x14, 1.0)
    half2v wx[8];
#pragma unroll
    for (int j = 0; j < 7; ++j)
        wx[j] = __builtin_amdgcn_cvt_pkrtz(W_ih[lane * II + 2 * j],
                                           W_ih[lane * II + 2 * j + 1]);
    wx[7] = __builtin_amdgcn_cvt_pkrtz(W_ih[lane * II + 14],
                                       b_ih[lane] + b_hh[lane]);

    const float* xb = x + (size_t)b * TT * II;
    _Float16* hrow = hs + (size_t)b * TT * HH + lane;
    const int4v* hb4 = (const int4v*)hbuf;

    // stage chunk 0 into xbuf[0]: lane ts packs x[b][ts][0..14] -> 8 pairs
    {
        float cf[II];
#pragma unroll
        for (int i = 0; i < II; ++i) cf[i] = xb[lane * II + i];
        int4v p0, p1;
        p0.x = h22i(__builtin_amdgcn_cvt_pkrtz(cf[0], cf[1]));
        p0.y = h22i(__builtin_amdgcn_cvt_pkrtz(cf[2], cf[3]));
        p0.z = h22i(__builtin_amdgcn_cvt_pkrtz(cf[4], cf[5]));
        p0.w = h22i(__builtin_amdgcn_cvt_pkrtz(cf[6], cf[7]));
        p1.x = h22i(__builtin_amdgcn_cvt_pkrtz(cf[8], cf[9]));
        p1.y = h22i(__builtin_amdgcn_cvt_pkrtz(cf[10], cf[11]));
        p1.z = h22i(__builtin_amdgcn_cvt_pkrtz(cf[12], cf[13]));
        p1.w = h22i(__builtin_amdgcn_cvt_pkrtz(cf[14], 1.0f));
        *(int4v*)&xbuf[0][lane * 8] = p0;
        *(int4v*)&xbuf[0][lane * 8 + 4] = p1;
    }
    hbuf[lane] = (_Float16)0.0f;    // h(-1) = 0

    // xproj accumulators for step 0 (read back slot 0; wave-synchronous)
    float xa[8];
    {
        const int4v xv0 = *(const int4v*)&xbuf[0][0];
        const int4v xv1 = *(const int4v*)&xbuf[0][4];
        xa[0] = FDOT2(i2h2(xv0.x), wx[0], 0.0f);
        xa[1] = FDOT2(i2h2(xv0.y), wx[1], 0.0f);
        xa[2] = FDOT2(i2h2(xv0.z), wx[2], 0.0f);
        xa[3] = FDOT2(i2h2(xv0.w), wx[3], 0.0f);
        xa[4] = FDOT2(i2h2(xv1.x), wx[4], 0.0f);
        xa[5] = FDOT2(i2h2(xv1.y), wx[5], 0.0f);
        xa[6] = FDOT2(i2h2(xv1.z), wx[6], 0.0f);
        xa[7] = FDOT2(i2h2(xv1.w), wx[7], 0.0f);
    }

    float h = 0.0f;

    auto step = [&](int t) {
        // broadcast reads of h(t-1): 8 uniform-address b128 (conflict-free)
        int4v hb[8];
#pragma unroll
        for (int q = 0; q < 8; ++q) hb[q] = hb4[q];

        // xbuf pairs for step t+1 (issued before the h(t) write in DS order)
        const int tn = t + 1;
        const int* xp = &xbuf[(tn >> 6) & 1][(tn & 63) * 8];
        const int4v xv0 = *(const int4v*)xp;
        const int4v xv1 = *(const int4v*)(xp + 4);

        // GEMV: 8 chains x depth 4, seeded by the precomputed xproj
        float a0 = xa[0], a1 = xa[1], a2 = xa[2], a3 = xa[3];
        float a4 = xa[4], a5 = xa[5], a6 = xa[6], a7 = xa[7];
#pragma unroll
        for (int r = 0; r < 4; ++r) {
            a0 = FDOT2(i2h2(hb[2 * r].x),     whh[8 * r + 0], a0);
            a1 = FDOT2(i2h2(hb[2 * r].y),     whh[8 * r + 1], a1);
            a2 = FDOT2(i2h2(hb[2 * r].z),     whh[8 * r + 2], a2);
            a3 = FDOT2(i2h2(hb[2 * r].w),     whh[8 * r + 3], a3);
            a4 = FDOT2(i2h2(hb[2 * r + 1].x), whh[8 * r + 4], a4);
            a5 = FDOT2(i2h2(hb[2 * r + 1].y), whh[8 * r + 5], a5);
            a6 = FDOT2(i2h2(hb[2 * r + 1].z), whh[8 * r + 6], a6);
            a7 = FDOT2(i2h2(hb[2 * r + 1].w), whh[8 * r + 7], a7);
        }
        h = fmaxf(((a0 + a1) + (a2 + a3)) + ((a4 + a5) + (a6 + a7)), 0.0f);
        const _Float16 hf = (_Float16)h;
        hbuf[lane] = hf;                       // publish h(t)
        hrow[(size_t)t * HH] = hf;             // 128B contiguous global store

        // xproj for t+1 (fills this step's LDS stall window)
        xa[0] = FDOT2(i2h2(xv0.x), wx[0], 0.0f);
        xa[1] = FDOT2(i2h2(xv0.y), wx[1], 0.0f);
        xa[2] = FDOT2(i2h2(xv0.z), wx[2], 0.0f);
        xa[3] = FDOT2(i2h2(xv0.w), wx[3], 0.0f);
        xa[4] = FDOT2(i2h2(xv1.x), wx[4], 0.0f);
        xa[5] = FDOT2(i2h2(xv1.y), wx[5], 0.0f);
        xa[6] = FDOT2(i2h2(xv1.z), wx[6], 0.0f);
        xa[7] = FDOT2(i2h2(xv1.w), wx[7], 0.0f);
    };

    for (int tc = 0; tc < TT; tc += 64) {
        // global prefetch of the next chunk (re-reads current on the last one)
        const int tnb = (tc + 64 < TT) ? (tc + 64) : tc;
        float nf[II];
#pragma unroll
        for (int i = 0; i < II; ++i)
            nf[i] = xb[(size_t)(tnb + lane) * II + i];

        for (int to = 0; to < 32; to += 8)
#pragma unroll
            for (int u = 0; u < 8; ++u) step(tc + to + u);

        // commit prefetched chunk into the other xbuf half (reads for t+1
        // only touch it from ts=63 onward; committed here at ts=32)
        {
            const int cb = ((tc >> 6) + 1) & 1;
            int4v p0, p1;
            p0.x = h22i(__builtin_amdgcn_cvt_pkrtz(nf[0], nf[1]));
            p0.y = h22i(__builtin_amdgcn_cvt_pkrtz(nf[2], nf[3]));
            p0.z = h22i(__builtin_amdgcn_cvt_pkrtz(nf[4], nf[5]));
            p0.w = h22i(__builtin_amdgcn_cvt_pkrtz(nf[6], nf[7]));
            p1.x = h22i(__builtin_amdgcn_cvt_pkrtz(nf[8], nf[9]));
            p1.y = h22i(__builtin_amdgcn_cvt_pkrtz(nf[10], nf[11]));
            p1.z = h22i(__builtin_amdgcn_cvt_pkrtz(nf[12], nf[13]));
            p1.w = h22i(__builtin_amdgcn_cvt_pkrtz(nf[14], 1.0f));
            *(int4v*)&xbuf[cb][lane * 8] = p0;
            *(int4v*)&xbuf[cb][lane * 8 + 4] = p1;
        }

        for (int to = 32; to < 64; to += 8)
#pragma unroll
            for (int u = 0; u < 8; ++u) step(tc + to + u);
    }
    h_last[b * HH + lane] = h;
}

// Decoder: one 16x16x64 tile per wave (16 consecutive (b,t) rows of one batch).
// hs read: 2KB contiguous per wave; out store: 704B contiguous per tile.
__global__ __launch_bounds__(256) void rnn_decode(
    const _Float16* __restrict__ hs, const float* __restrict__ W_dec,
    const float* __restrict__ b_dec, float* __restrict__ out)
{
    __shared__ __align__(16) _Float16 wl[16 * HH];
    const int tid = threadIdx.x;
    for (int i = tid; i < 16 * HH; i += 256)
        wl[i] = (_Float16)((i < OO * HH) ? W_dec[i] : 0.0f);
    __syncthreads();

    const int lane = tid & 63;
    const int wid  = tid >> 6;
    const int col  = lane & 15;
    const int quad = lane >> 4;
    const float bd = (col < OO) ? b_dec[col] : 0.0f;

    half8 bf0 = *(const half8*)&wl[col * HH + quad * 8];
    half8 bf1 = *(const half8*)&wl[col * HH + 32 + quad * 8];

    const size_t tile = (size_t)blockIdx.x * 4 + wid;   // 0..32767
    const size_t btb = tile * 16;
    const _Float16* ap = hs + (btb + (size_t)col) * HH + quad * 8;
    half8 a0 = *(const half8*)ap;
    half8 a1 = *(const half8*)(ap + 32);

    floatx4 acc = {0.0f, 0.0f, 0.0f, 0.0f};
    acc = __builtin_amdgcn_mfma_f32_16x16x32_f16(a0, bf0, acc, 0, 0, 0);
    acc = __builtin_amdgcn_mfma_f32_16x16x32_f16(a1, bf1, acc, 0, 0, 0);

    if (col < OO) {
#pragma unroll
        for (int r = 0; r < 4; ++r) {
            const size_t row = btb + (size_t)(quad * 4 + r);
            out[row * OO + col] = fmaxf(acc[r] + bd, 0.0f);
        }
    }
}

extern "C" void kernel_launch(void* const* d_in, const int* in_sizes, int n_in,
                              void* d_out, int out_size, void* d_ws, size_t ws_size,
                              hipStream_t stream) {
    const float* x     = (const float*)d_in[0];
    const float* W_ih  = (const float*)d_in[1];
    const float* b_ih  = (const float*)d_in[2];
    const float* W_hh  = (const float*)d_in[3];
    const float* b_hh  = (const float*)d_in[4];
    const float* W_dec = (const float*)d_in[5];
    const float* b_dec = (const float*)d_in[6];

    float* out    = (float*)d_out;
    float* h_last = out + (size_t)BB * TT * OO;   // second tuple output
    _Float16* hs  = (_Float16*)d_ws;              // [B][T][H] f16, 64 MiB

    rnn_rec<<<BB, 64, 0, stream>>>(x, W_ih, b_ih, W_hh, b_hh, hs, h_last);
    rnn_decode<<<8192, 256, 0, stream>>>(hs, W_dec, b_dec, out);
}

// Round 8
// 273.701 us; speedup vs baseline: 1.4671x; 1.0004x over previous
//
#include <hip/hip_runtime.h>
#include <hip/hip_fp16.h>
#include <stdint.h>

#define BB 512
#define TT 1024
#define II 15
#define HH 64
#define OO 11

typedef __fp16 half2v __attribute__((ext_vector_type(2)));
typedef _Float16 half8 __attribute__((ext_vector_type(8)));
typedef float floatx4 __attribute__((ext_vector_type(4)));
typedef int int4v __attribute__((ext_vector_type(4)));

union PK { int i; half2v h; float f; };

__device__ __forceinline__ half2v i2h2(int v) { PK u; u.i = v; return u.h; }
__device__ __forceinline__ int h22i(half2v v) { PK u; u.h = v; return u.i; }

__device__ __forceinline__ float FDOT2(half2v a, half2v b, float c) {
    return __builtin_amdgcn_fdot2(a, b, c, false);
}

__device__ __forceinline__ float lane_xor1(float v) {
    PK u; u.f = v;
    // quad_perm(1,0,3,2) = 0xB1 : lane -> lane^1
    u.i = __builtin_amdgcn_mov_dpp(u.i, 0xB1, 0xF, 0xF, false);
    return u.f;
}

// One wave per batch, lane = h_out. The 64-wide h broadcast is SPLIT across
// two pipes so less of it sits behind the LDS round-trip:
//   h[0..15]  : 8 packed pairs via v_readlane (in-register, wave-synchronous,
//               ready instantly -> fills the DS latency window)
//   h[16..63] : 24 pairs via SIX ds_read_b128 broadcast reads (was 8)
// Per-step DS program order: 6 h-reads -> h-write -> 2 x-reads, so the h-write
// is never delayed and the lgkmcnt drain for h covers only 6 reads.
// xproj(t+1) computed during step t (xa[8]); x double-buffered per 64 steps.
__global__ __launch_bounds__(64) void rnn_rec(
    const float* __restrict__ x, const float* __restrict__ W_ih,
    const float* __restrict__ b_ih, const float* __restrict__ W_hh,
    const float* __restrict__ b_hh, _Float16* __restrict__ hs,
    float* __restrict__ h_last)
{
    __shared__ __align__(16) int xbuf[2][64 * 8];  // [buf][step][8 packed pairs]
    __shared__ __align__(16) _Float16 hbuf[64];    // h_t, one f16 per lane
    const int b = blockIdx.x;
    const int lane = threadIdx.x;

    // recurrent weights: whh[p] = (W_hh[lane][2p], W_hh[lane][2p+1])
    half2v whh[32];
#pragma unroll
    for (int p = 0; p < 32; ++p)
        whh[p] = __builtin_amdgcn_cvt_pkrtz(W_hh[lane * HH + 2 * p],
                                            W_hh[lane * HH + 2 * p + 1]);
    // input weights; pair 7 = (w14, bias) matching x pair (x14, 1.0)
    half2v wx[8];
#pragma unroll
    for (int j = 0; j < 7; ++j)
        wx[j] = __builtin_amdgcn_cvt_pkrtz(W_ih[lane * II + 2 * j],
                                           W_ih[lane * II + 2 * j + 1]);
    wx[7] = __builtin_amdgcn_cvt_pkrtz(W_ih[lane * II + 14],
                                       b_ih[lane] + b_hh[lane]);

    const float* xb = x + (size_t)b * TT * II;
    _Float16* hrow = hs + (size_t)b * TT * HH + lane;
    const int4v* hb4 = (const int4v*)hbuf;

    // stage chunk 0 into xbuf[0]: lane ts packs x[b][ts][0..14] -> 8 pairs
    {
        float cf[II];
#pragma unroll
        for (int i = 0; i < II; ++i) cf[i] = xb[lane * II + i];
        int4v p0, p1;
        p0.x = h22i(__builtin_amdgcn_cvt_pkrtz(cf[0], cf[1]));
        p0.y = h22i(__builtin_amdgcn_cvt_pkrtz(cf[2], cf[3]));
        p0.z = h22i(__builtin_amdgcn_cvt_pkrtz(cf[4], cf[5]));
        p0.w = h22i(__builtin_amdgcn_cvt_pkrtz(cf[6], cf[7]));
        p1.x = h22i(__builtin_amdgcn_cvt_pkrtz(cf[8], cf[9]));
        p1.y = h22i(__builtin_amdgcn_cvt_pkrtz(cf[10], cf[11]));
        p1.z = h22i(__builtin_amdgcn_cvt_pkrtz(cf[12], cf[13]));
        p1.w = h22i(__builtin_amdgcn_cvt_pkrtz(cf[14], 1.0f));
        *(int4v*)&xbuf[0][lane * 8] = p0;
        *(int4v*)&xbuf[0][lane * 8 + 4] = p1;
    }
    hbuf[lane] = (_Float16)0.0f;    // h(-1) = 0

    // xproj accumulators for step 0 (read back slot 0; wave-synchronous)
    float xa[8];
    {
        const int4v xv0 = *(const int4v*)&xbuf[0][0];
        const int4v xv1 = *(const int4v*)&xbuf[0][4];
        xa[0] = FDOT2(i2h2(xv0.x), wx[0], 0.0f);
        xa[1] = FDOT2(i2h2(xv0.y), wx[1], 0.0f);
        xa[2] = FDOT2(i2h2(xv0.z), wx[2], 0.0f);
        xa[3] = FDOT2(i2h2(xv0.w), wx[3], 0.0f);
        xa[4] = FDOT2(i2h2(xv1.x), wx[4], 0.0f);
        xa[5] = FDOT2(i2h2(xv1.y), wx[5], 0.0f);
        xa[6] = FDOT2(i2h2(xv1.z), wx[6], 0.0f);
        xa[7] = FDOT2(i2h2(xv1.w), wx[7], 0.0f);
    }

    float h = 0.0f;
    int hpk = 0;   // packed (h[lane&~1], h[lane|1]) from previous step (h=0)

    auto step = [&](int t) {
        // LDS broadcast reads of h(t-1)[16..63]: 6 uniform-address b128
        int4v hb[6];
#pragma unroll
        for (int q = 0; q < 6; ++q) hb[q] = hb4[q + 2];

        // seed with precomputed xproj
        float a0 = xa[0], a1 = xa[1], a2 = xa[2], a3 = xa[3];
        float a4 = xa[4], a5 = xa[5], a6 = xa[6], a7 = xa[7];

        // register-broadcast path: h(t-1)[0..15] pairs live in even lanes'
        // hpk; readlane is wave-synchronous, no memory -> fills the DS stall
        a0 = FDOT2(i2h2(__builtin_amdgcn_readlane(hpk, 0)),  whh[0], a0);
        a1 = FDOT2(i2h2(__builtin_amdgcn_readlane(hpk, 2)),  whh[1], a1);
        a2 = FDOT2(i2h2(__builtin_amdgcn_readlane(hpk, 4)),  whh[2], a2);
        a3 = FDOT2(i2h2(__builtin_amdgcn_readlane(hpk, 6)),  whh[3], a3);
        a4 = FDOT2(i2h2(__builtin_amdgcn_readlane(hpk, 8)),  whh[4], a4);
        a5 = FDOT2(i2h2(__builtin_amdgcn_readlane(hpk, 10)), whh[5], a5);
        a6 = FDOT2(i2h2(__builtin_amdgcn_readlane(hpk, 12)), whh[6], a6);
        a7 = FDOT2(i2h2(__builtin_amdgcn_readlane(hpk, 14)), whh[7], a7);

        // LDS dots: round q consumes hb[q] (pairs 8+4q .. 11+4q)
#pragma unroll
        for (int q = 0; q < 6; ++q) {
            const int base = 8 + 4 * q;
            if ((q & 1) == 0) {
                a0 = FDOT2(i2h2(hb[q].x), whh[base + 0], a0);
                a1 = FDOT2(i2h2(hb[q].y), whh[base + 1], a1);
                a2 = FDOT2(i2h2(hb[q].z), whh[base + 2], a2);
                a3 = FDOT2(i2h2(hb[q].w), whh[base + 3], a3);
            } else {
                a4 = FDOT2(i2h2(hb[q].x), whh[base + 0], a4);
                a5 = FDOT2(i2h2(hb[q].y), whh[base + 1], a5);
                a6 = FDOT2(i2h2(hb[q].z), whh[base + 2], a6);
                a7 = FDOT2(i2h2(hb[q].w), whh[base + 3], a7);
            }
        }
        h = fmaxf(((a0 + a1) + (a2 + a3)) + ((a4 + a5) + (a6 + a7)), 0.0f);
        const _Float16 hf = (_Float16)h;
        hbuf[lane] = hf;                       // publish h(t)  (DS op #7)

        // x pairs for step t+1 (DS ops #8,#9 — issued AFTER the h write)
        const int tn = t + 1;
        const int* xp = &xbuf[(tn >> 6) & 1][(tn & 63) * 8];
        const int4v xv0 = *(const int4v*)xp;
        const int4v xv1 = *(const int4v*)(xp + 4);

        hrow[(size_t)t * HH] = hf;             // 128B contiguous global store

        // pack pair for next step's readlane path (off the DS pipe)
        hpk = h22i(__builtin_amdgcn_cvt_pkrtz(h, lane_xor1(h)));

        // xproj for t+1 (consumes xv late; fills residual stall)
        xa[0] = FDOT2(i2h2(xv0.x), wx[0], 0.0f);
        xa[1] = FDOT2(i2h2(xv0.y), wx[1], 0.0f);
        xa[2] = FDOT2(i2h2(xv0.z), wx[2], 0.0f);
        xa[3] = FDOT2(i2h2(xv0.w), wx[3], 0.0f);
        xa[4] = FDOT2(i2h2(xv1.x), wx[4], 0.0f);
        xa[5] = FDOT2(i2h2(xv1.y), wx[5], 0.0f);
        xa[6] = FDOT2(i2h2(xv1.z), wx[6], 0.0f);
        xa[7] = FDOT2(i2h2(xv1.w), wx[7], 0.0f);
    };

    for (int tc = 0; tc < TT; tc += 64) {
        // global prefetch of the next chunk (re-reads current on the last one)
        const int tnb = (tc + 64 < TT) ? (tc + 64) : tc;
        float nf[II];
#pragma unroll
        for (int i = 0; i < II; ++i)
            nf[i] = xb[(size_t)(tnb + lane) * II + i];

        for (int to = 0; to < 32; to += 8)
#pragma unroll
            for (int u = 0; u < 8; ++u) step(tc + to + u);

        // commit prefetched chunk into the other xbuf half (t+1 reads touch
        // it only from ts=63; committed here at ts=32)
        {
            const int cb = ((tc >> 6) + 1) & 1;
            int4v p0, p1;
            p0.x = h22i(__builtin_amdgcn_cvt_pkrtz(nf[0], nf[1]));
            p0.y = h22i(__builtin_amdgcn_cvt_pkrtz(nf[2], nf[3]));
            p0.z = h22i(__builtin_amdgcn_cvt_pkrtz(nf[4], nf[5]));
            p0.w = h22i(__builtin_amdgcn_cvt_pkrtz(nf[6], nf[7]));
            p1.x = h22i(__builtin_amdgcn_cvt_pkrtz(nf[8], nf[9]));
            p1.y = h22i(__builtin_amdgcn_cvt_pkrtz(nf[10], nf[11]));
            p1.z = h22i(__builtin_amdgcn_cvt_pkrtz(nf[12], nf[13]));
            p1.w = h22i(__builtin_amdgcn_cvt_pkrtz(nf[14], 1.0f));
            *(int4v*)&xbuf[cb][lane * 8] = p0;
            *(int4v*)&xbuf[cb][lane * 8 + 4] = p1;
        }

        for (int to = 32; to < 64; to += 8)
#pragma unroll
            for (int u = 0; u < 8; ++u) step(tc + to + u);
    }
    h_last[b * HH + lane] = h;
}

// Decoder: one 16x16x64 tile per wave (16 consecutive (b,t) rows of one batch).
// hs read: 2KB contiguous per wave; out store: 704B contiguous per tile.
__global__ __launch_bounds__(256) void rnn_decode(
    const _Float16* __restrict__ hs, const float* __restrict__ W_dec,
    const float* __restrict__ b_dec, float* __restrict__ out)
{
    __shared__ __align__(16) _Float16 wl[16 * HH];
    const int tid = threadIdx.x;
    for (int i = tid; i < 16 * HH; i += 256)
        wl[i] = (_Float16)((i < OO * HH) ? W_dec[i] : 0.0f);
    __syncthreads();

    const int lane = tid & 63;
    const int wid  = tid >> 6;
    const int col  = lane & 15;
    const int quad = lane >> 4;
    const float bd = (col < OO) ? b_dec[col] : 0.0f;

    half8 bf0 = *(const half8*)&wl[col * HH + quad * 8];
    half8 bf1 = *(const half8*)&wl[col * HH + 32 + quad * 8];

    const size_t tile = (size_t)blockIdx.x * 4 + wid;   // 0..32767
    const size_t btb = tile * 16;
    const _Float16* ap = hs + (btb + (size_t)col) * HH + quad * 8;
    half8 a0 = *(const half8*)ap;
    half8 a1 = *(const half8*)(ap + 32);

    floatx4 acc = {0.0f, 0.0f, 0.0f, 0.0f};
    acc = __builtin_amdgcn_mfma_f32_16x16x32_f16(a0, bf0, acc, 0, 0, 0);
    acc = __builtin_amdgcn_mfma_f32_16x16x32_f16(a1, bf1, acc, 0, 0, 0);

    if (col < OO) {
#pragma unroll
        for (int r = 0; r < 4; ++r) {
            const size_t row = btb + (size_t)(quad * 4 + r);
            out[row * OO + col] = fmaxf(acc[r] + bd, 0.0f);
        }
    }
}

extern "C" void kernel_launch(void* const* d_in, const int* in_sizes, int n_in,
                              void* d_out, int out_size, void* d_ws, size_t ws_size,
                              hipStream_t stream) {
    const float* x     = (const float*)d_in[0];
    const float* W_ih  = (const float*)d_in[1];
    const float* b_ih  = (const float*)d_in[2];
    const float* W_hh  = (const float*)d_in[3];
    const float* b_hh  = (const float*)d_in[4];
    const float* W_dec = (const float*)d_in[5];
    const float* b_dec = (const float*)d_in[6];

    float* out    = (float*)d_out;
    float* h_last = out + (size_t)BB * TT * OO;   // second tuple output
    _Float16* hs  = (_Float16*)d_ws;              // [B][T][H] f16, 64 MiB

    rnn_rec<<<BB, 64, 0, stream>>>(x, W_ih, b_ih, W_hh, b_hh, hs, h_last);
    rnn_decode<<<8192, 256, 0, stream>>>(hs, W_dec, b_dec, out);
}